// Round 9
// baseline (150.295 us; speedup 1.0000x reference)
//
#include <hip/hip_runtime.h>
#include <math.h>

// Problem constants (match reference)
#define B_     32
#define C_INP  128
#define C_OUTP 256
#define KS_    9
#define KK_    8
#define FD_    64
#define LL_    4096
#define PAD_   4

#define LPAD   (LL_ + 2 * PAD_)   // 4104 padded rows in XT

typedef unsigned short ushort_t;
typedef short bf16x8 __attribute__((ext_vector_type(8)));
typedef float f32x4 __attribute__((ext_vector_type(4)));
typedef float f32x16 __attribute__((ext_vector_type(16)));

__device__ __forceinline__ ushort_t f2bf(float f) {
    unsigned u = __float_as_uint(f);
    unsigned r = (u + 0x7FFFu + ((u >> 16) & 1u)) >> 16;
    return (ushort_t)r;
}

__device__ __forceinline__ void gload16(const void* g, void* l) {
    __builtin_amdgcn_global_load_lds(
        (const __attribute__((address_space(1))) unsigned int*)g,
        (__attribute__((address_space(3))) unsigned int*)l, 16, 0, 0);
}

// ---------------------------------------------------------------------------
// Kernel 1: routing MLP -> omega (B,K) and b_tilde (B,C_OUT), into workspace
// ---------------------------------------------------------------------------
__global__ __launch_bounds__(256) void routing_kernel(
    const float* __restrict__ Z, const float* __restrict__ z_in_w,
    const float* __restrict__ z_in_b, const float* __restrict__ w1,
    const float* __restrict__ b1, const float* __restrict__ w2,
    const float* __restrict__ b2, const float* __restrict__ bias_bank,
    float* __restrict__ omega_out, float* __restrict__ btilde_out)
{
    const int b = blockIdx.x;
    const int tid = threadIdx.x;
    __shared__ float s_z[FD_];
    __shared__ float s_proj[C_INP];
    __shared__ float s_h[FD_];
    __shared__ float s_logits[KK_];
    __shared__ float s_omega[KK_];

    if (tid < FD_) s_z[tid] = Z[b * FD_ + tid];
    __syncthreads();

    if (tid < C_INP) {
        float acc = z_in_b[tid];
        const float* w = z_in_w + tid * FD_;
        #pragma unroll 8
        for (int f = 0; f < FD_; ++f) acc = fmaf(w[f], s_z[f], acc);
        s_proj[tid] = acc;
    }
    __syncthreads();

    if (tid < FD_) {
        float acc = b1[tid];
        const float* w = w1 + tid * C_INP;
        #pragma unroll 8
        for (int c = 0; c < C_INP; ++c) acc = fmaf(w[c], s_proj[c], acc);
        s_h[tid] = fmaxf(acc, 0.0f);
    }
    __syncthreads();

    if (tid < KK_) {
        float acc = b2[tid];
        const float* w = w2 + tid * FD_;
        #pragma unroll 8
        for (int j = 0; j < FD_; ++j) acc = fmaf(w[j], s_h[j], acc);
        s_logits[tid] = acc;
    }
    __syncthreads();

    if (tid == 0) {
        float m = s_logits[0];
        #pragma unroll
        for (int k = 1; k < KK_; ++k) m = fmaxf(m, s_logits[k]);
        float e[KK_];
        float s = 0.0f;
        #pragma unroll
        for (int k = 0; k < KK_; ++k) { e[k] = expf(s_logits[k] - m); s += e[k]; }
        const float inv = 1.0f / s;
        #pragma unroll
        for (int k = 0; k < KK_; ++k) s_omega[k] = e[k] * inv;
    }
    __syncthreads();

    if (tid < KK_) omega_out[b * KK_ + tid] = s_omega[tid];

    {
        float acc = 0.0f;
        #pragma unroll
        for (int k = 0; k < KK_; ++k) acc = fmaf(s_omega[k], bias_bank[k * C_OUTP + tid], acc);
        btilde_out[b * C_OUTP + tid] = acc;
    }
}

// ---------------------------------------------------------------------------
// Kernel 2: weight mixing -> bf16 W~ in layout [b][t][o][c]
// ---------------------------------------------------------------------------
__global__ __launch_bounds__(256) void mix_kernel(
    const float* __restrict__ bank, const float* __restrict__ omega,
    ushort_t* __restrict__ wt)
{
    __shared__ float s_bank[KK_ * C_INP * KS_];  // 8*1152 fp32 = 36.9 KB
    __shared__ float s_om[B_ * KK_];             // 256 floats

    const int o = blockIdx.x;
    const int tid = threadIdx.x;

    s_om[tid] = omega[tid];                      // 32*8 == 256
    #pragma unroll
    for (int k = 0; k < KK_; ++k) {
        const float* src = bank + ((size_t)(k * C_OUTP + o)) * (C_INP * KS_);
        for (int i = tid; i < C_INP * KS_; i += 256)
            s_bank[k * (C_INP * KS_) + i] = src[i];
    }
    __syncthreads();

    for (int j = tid; j < KS_ * (C_INP / 2); j += 256) {
        const int t = j >> 6;
        const int c = (j & 63) * 2;
        float v0[KK_], v1[KK_];
        #pragma unroll
        for (int k = 0; k < KK_; ++k) {
            v0[k] = s_bank[k * (C_INP * KS_) + c * KS_ + t];
            v1[k] = s_bank[k * (C_INP * KS_) + (c + 1) * KS_ + t];
        }
        #pragma unroll
        for (int b = 0; b < B_; ++b) {
            float a0 = 0.0f, a1 = 0.0f;
            #pragma unroll
            for (int k = 0; k < KK_; ++k) {
                const float om = s_om[b * KK_ + k];
                a0 = fmaf(om, v0[k], a0);
                a1 = fmaf(om, v1[k], a1);
            }
            const unsigned packed = (unsigned)f2bf(a0) | ((unsigned)f2bf(a1) << 16);
            *(unsigned*)&wt[(((size_t)b * KS_ + t) * C_OUTP + o) * C_INP + c] = packed;
        }
    }
}

// ---------------------------------------------------------------------------
// Kernel 3: X (B,C,L) fp32 -> XT (B, L+8, C) bf16, with zeroed 4-row halos.
// ---------------------------------------------------------------------------
__global__ __launch_bounds__(256) void transpose_kernel(
    const float* __restrict__ X, ushort_t* __restrict__ XT)
{
    __shared__ ushort_t s_t[64 * 130];   // [l][c], c-dim padded 128->130

    const int tid = threadIdx.x;
    const int l0 = blockIdx.x * 64;
    const int b = blockIdx.y;

    const int ll = tid & 63;             // local l
    const int cq = tid >> 6;             // 0..3
    const float* xb = X + ((size_t)b * C_INP) * LL_;

    #pragma unroll 4
    for (int r = 0; r < 32; ++r) {
        const int c = r * 4 + cq;
        s_t[ll * 130 + c] = f2bf(xb[(size_t)c * LL_ + l0 + ll]);
    }
    __syncthreads();

    ushort_t* xtb = XT + (size_t)b * LPAD * C_INP;
    for (int it = tid; it < 64 * 64; it += 256) {
        const int row = it >> 6;
        const int p = it & 63;
        const unsigned lo = s_t[row * 130 + p * 2];
        const unsigned hi = s_t[row * 130 + p * 2 + 1];
        *(unsigned*)(xtb + ((size_t)(4 + l0 + row)) * C_INP + p * 2) = lo | (hi << 16);
    }
    if (l0 == 0) {
        const int row = tid >> 6, p = tid & 63;
        *(unsigned*)(xtb + (size_t)row * C_INP + p * 2) = 0u;
    }
    if (l0 == LL_ - 64) {
        const int row = tid >> 6, p = tid & 63;
        *(unsigned*)(xtb + ((size_t)(LL_ + PAD_ + row)) * C_INP + p * 2) = 0u;
    }
}

// ---------------------------------------------------------------------------
// Kernel 4: implicit-GEMM conv, 32x32x16 MFMA (4061 FLOP/cy vs 3378 for
//   16x16x32, m119), R6 ring shell: 512 thr, tile 256o x 256l, 8 waves
//   2m x 4n (wave 128o x 64l = 4m x 2n frags of 32x32).
//   X resident in sX (264x128, slot^(row&7) swizzle, staged once).
//   W: 36 K=32 slabs through 4-slot ring (4x16KB); 64B rows with
//   slot^( (row>>1)&3 ) swizzle -> conflict-free A-reads (R6 had 8-way).
//   Prefetch depth 3, boundary s_waitcnt vmcnt(4) (never 0 in-loop).
//   A/B frag: row/col = lane&31, k = 8*(lane>>5)+e (pattern verified on
//   16x16x32); C/D: col=lane&31, row=(r&3)+8*(r>>2)+4*(lane>>5) [m74/m101].
// ---------------------------------------------------------------------------
__global__ __launch_bounds__(512, 2) void gemm_kernel(
    const ushort_t* __restrict__ XT, const ushort_t* __restrict__ WT,
    const float* __restrict__ btilde, float* __restrict__ Y)
{
    __shared__ __align__(16) ushort_t sX[264 * 128];     // 67.6 KB
    __shared__ __align__(16) ushort_t sWr[4][256 * 32];  // 4 x 16 KB ring

    const int tid = threadIdx.x;
    const int wid = tid >> 6;
    const int lane = tid & 63;

    // bijective XCD swizzle: 512 wgs, 8 XCDs
    const int wg = blockIdx.x;
    const int logical = (wg & 7) * 64 + (wg >> 3);
    const int b  = logical >> 4;          // 16 l-tiles per batch
    const int l0 = (logical & 15) << 8;   // 0..3840

    const ushort_t* xtb = XT + ((size_t)b * LPAD + l0) * C_INP;
    const ushort_t* wtb = WT + (size_t)b * KS_ * C_OUTP * C_INP;

    // ---- prologue: stage sX (4224 x 16B, pre-swizzled src) + ring 0,1,2 ----
    for (int g = tid; g < 4224; g += 512) {
        const int row = g >> 4;
        const int pcp = g & 15;
        gload16(xtb + row * C_INP + ((pcp ^ (row & 7)) * 8), sX + g * 8);
    }
    #pragma unroll
    for (int p = 0; p < 3; ++p) {          // slabs 0..2 : t=0, q=p
        ushort_t* wd = sWr[p];
        const ushort_t* wsp = wtb + p * 32;
        #pragma unroll
        for (int itr = 0; itr < 2; ++itr) {
            const int g = itr * 512 + tid;
            const int row = g >> 2;
            const int sp = g & 3;
            gload16(wsp + row * C_INP + ((sp ^ ((row >> 1) & 3)) * 8), wd + g * 8);
        }
    }
    __syncthreads();                        // full drain once (prologue only)

    const int l31 = lane & 31;
    const int lh2 = lane >> 5;              // 0..1
    const int wm0 = (wid >> 2) * 128;       // 2 m-wave-groups
    const int wn0 = (wid & 3) * 64;         // 4 n-wave-groups

    f32x16 acc[4][2];
    #pragma unroll
    for (int i = 0; i < 4; ++i)
        #pragma unroll
        for (int j = 0; j < 2; ++j)
            acc[i][j] = (f32x16)(0.0f);

    #pragma unroll 1
    for (int s = 0; s < 36; ++s) {
        const int t = s >> 2;
        const int q = s & 3;
        int s3 = s + 3; if (s3 >= 36) s3 -= 36;       // wraparound prefetch
        const ushort_t* wr = sWr[s & 3];
        ushort_t* wdst = sWr[s3 & 3];                  // == (s+3)&3 (36%4==0)
        const ushort_t* wsrc = wtb + (size_t)(s3 >> 2) * (C_OUTP * C_INP) + (s3 & 3) * 32;

        // ---- issue prefetch (2 x gload16 per thread) ----
        #pragma unroll
        for (int itr = 0; itr < 2; ++itr) {
            const int g = itr * 512 + tid;
            const int row = g >> 2;
            const int sp = g & 3;
            gload16(wsrc + row * C_INP + ((sp ^ ((row >> 1) & 3)) * 8), wdst + g * 8);
        }

        // ---- ds_reads: A from ring, B from resident sX ----
        bf16x8 a[4][2], bx[2][2];
        #pragma unroll
        for (int mf = 0; mf < 4; ++mf) {
            const int arow = wm0 + mf * 32 + l31;
            const int xr = (arow >> 1) & 3;
            #pragma unroll
            for (int ks = 0; ks < 2; ++ks)
                a[mf][ks] = *(const bf16x8*)&wr[arow * 32 + (((ks * 2 + lh2) ^ xr) << 3)];
        }
        #pragma unroll
        for (int nf = 0; nf < 2; ++nf) {
            const int brow = wn0 + t + nf * 32 + l31;
            #pragma unroll
            for (int ks = 0; ks < 2; ++ks) {
                const int sl = (q * 4 + ks * 2 + lh2) ^ (brow & 7);
                bx[nf][ks] = *(const bf16x8*)&sX[brow * 128 + sl * 8];
            }
        }

        __builtin_amdgcn_s_setprio(1);
        #pragma unroll
        for (int ks = 0; ks < 2; ++ks)
            #pragma unroll
            for (int mf = 0; mf < 4; ++mf)
                #pragma unroll
                for (int nf = 0; nf < 2; ++nf)
                    acc[mf][nf] = __builtin_amdgcn_mfma_f32_32x32x16_bf16(
                        a[mf][ks], bx[nf][ks], acc[mf][nf], 0, 0, 0);
        __builtin_amdgcn_s_setprio(0);

        // ---- boundary: keep newest 4 loads in flight (slabs s+2, s+3) ----
        asm volatile("s_waitcnt vmcnt(4)" ::: "memory");
        __builtin_amdgcn_s_barrier();
        __builtin_amdgcn_sched_barrier(0);
    }
    asm volatile("s_waitcnt vmcnt(0)" ::: "memory");

    // ---- epilogue: Y[b, o, l] = acc + btilde[b, o] ----
    // C/D layout: col = lane&31, row = (r&3) + 8*(r>>2) + 4*(lane>>5)
    #pragma unroll
    for (int mf = 0; mf < 4; ++mf) {
        const int rbase = wm0 + mf * 32 + 4 * lh2;
        #pragma unroll
        for (int rq = 0; rq < 4; ++rq) {
            const float4 bt = *(const float4*)&btilde[b * C_OUTP + rbase + 8 * rq];
            #pragma unroll
            for (int nf = 0; nf < 2; ++nf) {
                const int col = l0 + wn0 + nf * 32 + l31;
                float* yp = Y + ((size_t)(b * C_OUTP + rbase + 8 * rq)) * LL_ + col;
                yp[0]        = acc[mf][nf][rq * 4 + 0] + bt.x;
                yp[LL_]      = acc[mf][nf][rq * 4 + 1] + bt.y;
                yp[2 * LL_]  = acc[mf][nf][rq * 4 + 2] + bt.z;
                yp[3 * LL_]  = acc[mf][nf][rq * 4 + 3] + bt.w;
            }
        }
    }
}

// ---------------------------------------------------------------------------
// Fallback fp32 direct conv (used only if workspace is too small)
// ---------------------------------------------------------------------------
#define O_TILE 8
#define T_PAD  12
__global__ __launch_bounds__(256) void conv_kernel(
    const float* __restrict__ X, const float* __restrict__ bank,
    const float* __restrict__ omega, const float* __restrict__ btilde,
    float* __restrict__ Y)
{
    __shared__ __align__(16) float s_w[C_INP * O_TILE * T_PAD];
    __shared__ float s_om[KK_];

    const int tid = threadIdx.x;
    const int o_base = blockIdx.x * O_TILE;
    const int b = blockIdx.y;

    if (tid < KK_) s_om[tid] = omega[b * KK_ + tid];
    __syncthreads();

    {
        const size_t kstride = (size_t)C_OUTP * C_INP * KS_;
        const float* bank_base = bank + (size_t)o_base * C_INP * KS_;
        for (int idx = tid; idx < O_TILE * C_INP * KS_; idx += 256) {
            const int o = idx / (C_INP * KS_);
            const int rem = idx - o * (C_INP * KS_);
            const int c = rem / KS_;
            const int t = rem - c * KS_;
            const float* p = bank_base + idx;
            float acc = 0.0f;
            #pragma unroll
            for (int k = 0; k < KK_; ++k) acc = fmaf(s_om[k], p[k * kstride], acc);
            s_w[(c * O_TILE + o) * T_PAD + t] = acc;
        }
    }
    __syncthreads();

    const int og = tid >> 7;
    const int lg = tid & 127;
    const float* xb = X + (size_t)b * C_INP * LL_;

    float bt[4];
    #pragma unroll
    for (int o = 0; o < 4; ++o) bt[o] = btilde[b * C_OUTP + o_base + og * 4 + o];

    for (int it = 0; it < 4; ++it) {
        const int l0 = it * 1024 + lg * 8;
        const int lx = l0 - PAD_;
        const bool fast = (lx >= 0) && (lx + 16 <= LL_);

        float acc[4][8];
        #pragma unroll
        for (int o = 0; o < 4; ++o)
            #pragma unroll
            for (int j = 0; j < 8; ++j) acc[o][j] = 0.0f;

        #pragma unroll 1
        for (int c = 0; c < C_INP; ++c) {
            const float* xrow = xb + (size_t)c * LL_;
            float x[16];
            if (fast) {
                const float4* p = reinterpret_cast<const float4*>(xrow + lx);
                const float4 a0 = p[0], a1 = p[1], a2 = p[2], a3 = p[3];
                x[0]=a0.x; x[1]=a0.y; x[2]=a0.z; x[3]=a0.w;
                x[4]=a1.x; x[5]=a1.y; x[6]=a1.z; x[7]=a1.w;
                x[8]=a2.x; x[9]=a2.y; x[10]=a2.z; x[11]=a2.w;
                x[12]=a3.x; x[13]=a3.y; x[14]=a3.z; x[15]=a3.w;
            } else {
                #pragma unroll
                for (int j = 0; j < 16; ++j) {
                    const int q = lx + j;
                    x[j] = (q >= 0 && q < LL_) ? xrow[q] : 0.0f;
                }
            }
            const float* wp = &s_w[(c * O_TILE + og * 4) * T_PAD];
            #pragma unroll
            for (int o = 0; o < 4; ++o) {
                #pragma unroll
                for (int t = 0; t < KS_; ++t) {
                    const float wv = wp[o * T_PAD + t];
                    #pragma unroll
                    for (int j = 0; j < 8; ++j)
                        acc[o][j] = fmaf(wv, x[j + t], acc[o][j]);
                }
            }
        }

        float* yb = Y + ((size_t)(b * C_OUTP + o_base + og * 4)) * LL_ + l0;
        #pragma unroll
        for (int o = 0; o < 4; ++o) {
            float4 r0, r1;
            r0.x = acc[o][0] + bt[o]; r0.y = acc[o][1] + bt[o];
            r0.z = acc[o][2] + bt[o]; r0.w = acc[o][3] + bt[o];
            r1.x = acc[o][4] + bt[o]; r1.y = acc[o][5] + bt[o];
            r1.z = acc[o][6] + bt[o]; r1.w = acc[o][7] + bt[o];
            float4* yp = reinterpret_cast<float4*>(yb + (size_t)o * LL_);
            yp[0] = r0; yp[1] = r1;
        }
    }
}

// ---------------------------------------------------------------------------
extern "C" void kernel_launch(void* const* d_in, const int* in_sizes, int n_in,
                              void* d_out, int out_size, void* d_ws, size_t ws_size,
                              hipStream_t stream)
{
    const float* X         = (const float*)d_in[0];
    const float* Z         = (const float*)d_in[1];
    const float* z_in_w    = (const float*)d_in[2];
    const float* z_in_b    = (const float*)d_in[3];
    const float* w1        = (const float*)d_in[4];
    const float* b1        = (const float*)d_in[5];
    const float* w2        = (const float*)d_in[6];
    const float* b2        = (const float*)d_in[7];
    const float* bank      = (const float*)d_in[8];
    const float* bias_bank = (const float*)d_in[9];
    float* out = (float*)d_out;

    // workspace layout
    char* ws = (char*)d_ws;
    float* omega  = (float*)ws;                               // 256 f = 1 KB
    float* btilde = (float*)(ws + 1024);                      // 8192 f = 32 KB
    ushort_t* wt  = (ushort_t*)(ws + 1024 + 32768);           // 18,874,368 B
    ushort_t* XT  = (ushort_t*)(ws + 1024 + 32768 + (size_t)B_ * KS_ * C_OUTP * C_INP * 2);
    const size_t WS_NEEDED = 1024 + 32768
        + (size_t)B_ * KS_ * C_OUTP * C_INP * 2
        + (size_t)B_ * LPAD * C_INP * 2;                      // ~52.5 MB

    routing_kernel<<<B_, 256, 0, stream>>>(Z, z_in_w, z_in_b, w1, b1, w2, b2,
                                           bias_bank, omega, btilde);

    if (ws_size >= WS_NEEDED) {
        mix_kernel<<<C_OUTP, 256, 0, stream>>>(bank, omega, wt);
        transpose_kernel<<<dim3(LL_ / 64, B_), 256, 0, stream>>>(X, XT);
        gemm_kernel<<<512, 512, 0, stream>>>(XT, wt, btilde, out);
    } else {
        dim3 grid(C_OUTP / O_TILE, B_);
        conv_kernel<<<grid, 256, 0, stream>>>(X, bank, omega, btilde, out);
    }
}

// Round 10
// 127.549 us; speedup vs baseline: 1.1783x; 1.1783x over previous
//
#include <hip/hip_runtime.h>
#include <math.h>

// Problem constants (match reference)
#define B_     32
#define C_INP  128
#define C_OUTP 256
#define KS_    9
#define KK_    8
#define FD_    64
#define LL_    4096
#define PAD_   4

#define LPAD   (LL_ + 2 * PAD_)   // 4104 padded rows in XT

typedef unsigned short ushort_t;
typedef short bf16x8 __attribute__((ext_vector_type(8)));
typedef float f32x4 __attribute__((ext_vector_type(4)));

__device__ __forceinline__ ushort_t f2bf(float f) {
    unsigned u = __float_as_uint(f);
    unsigned r = (u + 0x7FFFu + ((u >> 16) & 1u)) >> 16;
    return (ushort_t)r;
}

__device__ __forceinline__ void gload16(const void* g, void* l) {
    __builtin_amdgcn_global_load_lds(
        (const __attribute__((address_space(1))) unsigned int*)g,
        (__attribute__((address_space(3))) unsigned int*)l, 16, 0, 0);
}

// ---------------------------------------------------------------------------
// Kernel 1: routing MLP -> omega (B,K) and b_tilde (B,C_OUT), into workspace
// ---------------------------------------------------------------------------
__global__ __launch_bounds__(256) void routing_kernel(
    const float* __restrict__ Z, const float* __restrict__ z_in_w,
    const float* __restrict__ z_in_b, const float* __restrict__ w1,
    const float* __restrict__ b1, const float* __restrict__ w2,
    const float* __restrict__ b2, const float* __restrict__ bias_bank,
    float* __restrict__ omega_out, float* __restrict__ btilde_out)
{
    const int b = blockIdx.x;
    const int tid = threadIdx.x;
    __shared__ float s_z[FD_];
    __shared__ float s_proj[C_INP];
    __shared__ float s_h[FD_];
    __shared__ float s_logits[KK_];
    __shared__ float s_omega[KK_];

    if (tid < FD_) s_z[tid] = Z[b * FD_ + tid];
    __syncthreads();

    if (tid < C_INP) {
        float acc = z_in_b[tid];
        const float* w = z_in_w + tid * FD_;
        #pragma unroll 8
        for (int f = 0; f < FD_; ++f) acc = fmaf(w[f], s_z[f], acc);
        s_proj[tid] = acc;
    }
    __syncthreads();

    if (tid < FD_) {
        float acc = b1[tid];
        const float* w = w1 + tid * C_INP;
        #pragma unroll 8
        for (int c = 0; c < C_INP; ++c) acc = fmaf(w[c], s_proj[c], acc);
        s_h[tid] = fmaxf(acc, 0.0f);
    }
    __syncthreads();

    if (tid < KK_) {
        float acc = b2[tid];
        const float* w = w2 + tid * FD_;
        #pragma unroll 8
        for (int j = 0; j < FD_; ++j) acc = fmaf(w[j], s_h[j], acc);
        s_logits[tid] = acc;
    }
    __syncthreads();

    if (tid == 0) {
        float m = s_logits[0];
        #pragma unroll
        for (int k = 1; k < KK_; ++k) m = fmaxf(m, s_logits[k]);
        float e[KK_];
        float s = 0.0f;
        #pragma unroll
        for (int k = 0; k < KK_; ++k) { e[k] = expf(s_logits[k] - m); s += e[k]; }
        const float inv = 1.0f / s;
        #pragma unroll
        for (int k = 0; k < KK_; ++k) s_omega[k] = e[k] * inv;
    }
    __syncthreads();

    if (tid < KK_) omega_out[b * KK_ + tid] = s_omega[tid];

    {
        float acc = 0.0f;
        #pragma unroll
        for (int k = 0; k < KK_; ++k) acc = fmaf(s_omega[k], bias_bank[k * C_OUTP + tid], acc);
        btilde_out[b * C_OUTP + tid] = acc;
    }
}

// ---------------------------------------------------------------------------
// Kernel 2: weight mixing -> bf16 W~ in layout [b][t][o][c]
// ---------------------------------------------------------------------------
__global__ __launch_bounds__(256) void mix_kernel(
    const float* __restrict__ bank, const float* __restrict__ omega,
    ushort_t* __restrict__ wt)
{
    __shared__ float s_bank[KK_ * C_INP * KS_];  // 8*1152 fp32 = 36.9 KB
    __shared__ float s_om[B_ * KK_];             // 256 floats

    const int o = blockIdx.x;
    const int tid = threadIdx.x;

    s_om[tid] = omega[tid];                      // 32*8 == 256
    #pragma unroll
    for (int k = 0; k < KK_; ++k) {
        const float* src = bank + ((size_t)(k * C_OUTP + o)) * (C_INP * KS_);
        for (int i = tid; i < C_INP * KS_; i += 256)
            s_bank[k * (C_INP * KS_) + i] = src[i];
    }
    __syncthreads();

    for (int j = tid; j < KS_ * (C_INP / 2); j += 256) {
        const int t = j >> 6;
        const int c = (j & 63) * 2;
        float v0[KK_], v1[KK_];
        #pragma unroll
        for (int k = 0; k < KK_; ++k) {
            v0[k] = s_bank[k * (C_INP * KS_) + c * KS_ + t];
            v1[k] = s_bank[k * (C_INP * KS_) + (c + 1) * KS_ + t];
        }
        #pragma unroll
        for (int b = 0; b < B_; ++b) {
            float a0 = 0.0f, a1 = 0.0f;
            #pragma unroll
            for (int k = 0; k < KK_; ++k) {
                const float om = s_om[b * KK_ + k];
                a0 = fmaf(om, v0[k], a0);
                a1 = fmaf(om, v1[k], a1);
            }
            const unsigned packed = (unsigned)f2bf(a0) | ((unsigned)f2bf(a1) << 16);
            *(unsigned*)&wt[(((size_t)b * KS_ + t) * C_OUTP + o) * C_INP + c] = packed;
        }
    }
}

// ---------------------------------------------------------------------------
// Kernel 3: X (B,C,L) fp32 -> XT (B, L+8, C) bf16, with zeroed 4-row halos.
// ---------------------------------------------------------------------------
__global__ __launch_bounds__(256) void transpose_kernel(
    const float* __restrict__ X, ushort_t* __restrict__ XT)
{
    __shared__ ushort_t s_t[64 * 130];   // [l][c], c-dim padded 128->130

    const int tid = threadIdx.x;
    const int l0 = blockIdx.x * 64;
    const int b = blockIdx.y;

    const int ll = tid & 63;             // local l
    const int cq = tid >> 6;             // 0..3
    const float* xb = X + ((size_t)b * C_INP) * LL_;

    #pragma unroll 4
    for (int r = 0; r < 32; ++r) {
        const int c = r * 4 + cq;
        s_t[ll * 130 + c] = f2bf(xb[(size_t)c * LL_ + l0 + ll]);
    }
    __syncthreads();

    ushort_t* xtb = XT + (size_t)b * LPAD * C_INP;
    for (int it = tid; it < 64 * 64; it += 256) {
        const int row = it >> 6;
        const int p = it & 63;
        const unsigned lo = s_t[row * 130 + p * 2];
        const unsigned hi = s_t[row * 130 + p * 2 + 1];
        *(unsigned*)(xtb + ((size_t)(4 + l0 + row)) * C_INP + p * 2) = lo | (hi << 16);
    }
    if (l0 == 0) {
        const int row = tid >> 6, p = tid & 63;
        *(unsigned*)(xtb + (size_t)row * C_INP + p * 2) = 0u;
    }
    if (l0 == LL_ - 64) {
        const int row = tid >> 6, p = tid & 63;
        *(unsigned*)(xtb + ((size_t)(LL_ + PAD_ + row)) * C_INP + p * 2) = 0u;
    }
}

// ---------------------------------------------------------------------------
// Kernel 4: implicit-GEMM conv — R4 occupancy shell + counted-vmcnt ring.
//   256 threads, tile 128o x 128l, 4 waves (2m x 2n, wave 64x64, 16x16x32).
//   LDS 67.6 KB -> 2 blocks/CU (cross-block latency cover, m114).
//   sX: 136x128 resident, slot16 ^= (row&7)  [R4-verified conflict-free].
//   sW: 4-slot ring of K=32 slabs (128 rows x 64B), slot4 ^= (row>>1)&3
//       (derived conflict-free for 16-row x 4-slot A-read geometry).
//   36 slabs; 2 gloads/thread/slab prefetch depth 3 (wraparound);
//   ONE barrier/slab with s_waitcnt vmcnt(4) — never 0 in-loop (T4).
// ---------------------------------------------------------------------------
__global__ __launch_bounds__(256, 2) void gemm_kernel(
    const ushort_t* __restrict__ XT, const ushort_t* __restrict__ WT,
    const float* __restrict__ btilde, float* __restrict__ Y)
{
    __shared__ __align__(16) ushort_t sX[136 * 128];     // 34816 B
    __shared__ __align__(16) ushort_t sWr[4][128 * 32];  // 4 x 8192 B

    const int tid = threadIdx.x;
    const int wid = tid >> 6;
    const int lane = tid & 63;

    // bijective XCD swizzle: 2048 wgs, 8 XCDs; same-batch blocks co-located
    const int wg = blockIdx.x;
    const int logical = (wg & 7) * 256 + (wg >> 3);
    const int b  = logical >> 6;          // 64 blocks per batch
    const int rem = logical & 63;
    const int o0 = (rem >> 5) << 7;       // 0 or 128
    const int l0 = (rem & 31) << 7;       // 0..3968

    const ushort_t* xtb = XT + ((size_t)b * LPAD + l0) * C_INP;
    const ushort_t* wtb = WT + ((size_t)b * KS_ * C_OUTP + o0) * C_INP;

    // ---- prologue: stage sX (2176 x 16B, pre-swizzled src) ----
    for (int g = tid; g < 2176; g += 256) {
        const int row = g >> 4;
        const int pcp = g & 15;
        gload16(xtb + row * C_INP + ((pcp ^ (row & 7)) * 8), sX + g * 8);
    }
    // ---- ring slabs 0..2 (t=0, q=p), pre-swizzled src ----
    #pragma unroll
    for (int p = 0; p < 3; ++p) {
        ushort_t* wd = sWr[p];
        #pragma unroll
        for (int itr = 0; itr < 2; ++itr) {
            const int g = itr * 256 + tid;
            const int row = g >> 2;
            const int sp = g & 3;
            gload16(wtb + row * C_INP + p * 32 + ((sp ^ ((row >> 1) & 3)) * 8),
                    wd + g * 8);
        }
    }
    __syncthreads();                        // full drain once (prologue only)

    const int ln15 = lane & 15;
    const int lh = lane >> 4;               // 0..3
    const int wm0 = (wid >> 1) * 64;        // 2 m-waves
    const int wn0 = (wid & 1) * 64;         // 2 n-waves

    f32x4 acc[4][4];
    #pragma unroll
    for (int i = 0; i < 4; ++i)
        #pragma unroll
        for (int j = 0; j < 4; ++j) acc[i][j] = (f32x4){0.f, 0.f, 0.f, 0.f};

    #pragma unroll 1
    for (int s = 0; s < 36; ++s) {
        const int t = s >> 2;
        const int q = s & 3;
        int s3 = s + 3; if (s3 >= 36) s3 -= 36;       // wraparound prefetch
        const ushort_t* wr = sWr[s & 3];
        ushort_t* wdst = sWr[s3 & 3];                  // == (s+3)&3 (36%4==0)
        const ushort_t* wsrc = wtb + (size_t)(s3 >> 2) * (C_OUTP * C_INP) + (s3 & 3) * 32;

        // ---- ds_reads: A from ring slot, B from resident sX ----
        bf16x8 a[4], bx[4];
        #pragma unroll
        for (int i = 0; i < 4; ++i) {
            const int arow = wm0 + i * 16 + ln15;
            a[i] = *(const bf16x8*)&sWr[s & 3][arow * 32 + ((lh ^ ((arow >> 1) & 3)) << 3)];
        }
        #pragma unroll
        for (int j = 0; j < 4; ++j) {
            const int brow = wn0 + t + j * 16 + ln15;
            bx[j] = *(const bf16x8*)&sX[brow * 128 + (((q * 4 + lh) ^ (brow & 7)) << 3)];
        }
        (void)wr;

        // ---- issue prefetch for slab s+3 (2 gloads/thread) ----
        #pragma unroll
        for (int itr = 0; itr < 2; ++itr) {
            const int g = itr * 256 + tid;
            const int row = g >> 2;
            const int sp = g & 3;
            gload16(wsrc + row * C_INP + ((sp ^ ((row >> 1) & 3)) * 8), wdst + g * 8);
        }

        __builtin_amdgcn_s_setprio(1);
        #pragma unroll
        for (int i = 0; i < 4; ++i)
            #pragma unroll
            for (int j = 0; j < 4; ++j)
                acc[i][j] = __builtin_amdgcn_mfma_f32_16x16x32_bf16(
                    a[i], bx[j], acc[i][j], 0, 0, 0);
        __builtin_amdgcn_s_setprio(0);

        // ---- boundary: wait slab s+1 ready (6 outstanding - 2) ----
        asm volatile("s_waitcnt vmcnt(4)" ::: "memory");
        __builtin_amdgcn_s_barrier();
        __builtin_amdgcn_sched_barrier(0);
    }
    asm volatile("s_waitcnt vmcnt(0)" ::: "memory");

    // ---- epilogue: Y[b, o, l] = acc + btilde[b, o]  (R4-verified layout) ----
    #pragma unroll
    for (int i = 0; i < 4; ++i) {
        const int obase = o0 + wm0 + i * 16 + lh * 4;
        const float4 bt = *(const float4*)&btilde[b * C_OUTP + obase];
        #pragma unroll
        for (int j = 0; j < 4; ++j) {
            const int lcol = l0 + wn0 + j * 16 + ln15;
            float* yp = Y + ((size_t)(b * C_OUTP + obase)) * LL_ + lcol;
            yp[0]           = acc[i][j][0] + bt.x;
            yp[LL_]         = acc[i][j][1] + bt.y;
            yp[2 * LL_]     = acc[i][j][2] + bt.z;
            yp[3 * LL_]     = acc[i][j][3] + bt.w;
        }
    }
}

// ---------------------------------------------------------------------------
// Fallback fp32 direct conv (used only if workspace is too small)
// ---------------------------------------------------------------------------
#define O_TILE 8
#define T_PAD  12
__global__ __launch_bounds__(256) void conv_kernel(
    const float* __restrict__ X, const float* __restrict__ bank,
    const float* __restrict__ omega, const float* __restrict__ btilde,
    float* __restrict__ Y)
{
    __shared__ __align__(16) float s_w[C_INP * O_TILE * T_PAD];
    __shared__ float s_om[KK_];

    const int tid = threadIdx.x;
    const int o_base = blockIdx.x * O_TILE;
    const int b = blockIdx.y;

    if (tid < KK_) s_om[tid] = omega[b * KK_ + tid];
    __syncthreads();

    {
        const size_t kstride = (size_t)C_OUTP * C_INP * KS_;
        const float* bank_base = bank + (size_t)o_base * C_INP * KS_;
        for (int idx = tid; idx < O_TILE * C_INP * KS_; idx += 256) {
            const int o = idx / (C_INP * KS_);
            const int rem = idx - o * (C_INP * KS_);
            const int c = rem / KS_;
            const int t = rem - c * KS_;
            const float* p = bank_base + idx;
            float acc = 0.0f;
            #pragma unroll
            for (int k = 0; k < KK_; ++k) acc = fmaf(s_om[k], p[k * kstride], acc);
            s_w[(c * O_TILE + o) * T_PAD + t] = acc;
        }
    }
    __syncthreads();

    const int og = tid >> 7;
    const int lg = tid & 127;
    const float* xb = X + (size_t)b * C_INP * LL_;

    float bt[4];
    #pragma unroll
    for (int o = 0; o < 4; ++o) bt[o] = btilde[b * C_OUTP + o_base + og * 4 + o];

    for (int it = 0; it < 4; ++it) {
        const int l0 = it * 1024 + lg * 8;
        const int lx = l0 - PAD_;
        const bool fast = (lx >= 0) && (lx + 16 <= LL_);

        float acc[4][8];
        #pragma unroll
        for (int o = 0; o < 4; ++o)
            #pragma unroll
            for (int j = 0; j < 8; ++j) acc[o][j] = 0.0f;

        #pragma unroll 1
        for (int c = 0; c < C_INP; ++c) {
            const float* xrow = xb + (size_t)c * LL_;
            float x[16];
            if (fast) {
                const float4* p = reinterpret_cast<const float4*>(xrow + lx);
                const float4 a0 = p[0], a1 = p[1], a2 = p[2], a3 = p[3];
                x[0]=a0.x; x[1]=a0.y; x[2]=a0.z; x[3]=a0.w;
                x[4]=a1.x; x[5]=a1.y; x[6]=a1.z; x[7]=a1.w;
                x[8]=a2.x; x[9]=a2.y; x[10]=a2.z; x[11]=a2.w;
                x[12]=a3.x; x[13]=a3.y; x[14]=a3.z; x[15]=a3.w;
            } else {
                #pragma unroll
                for (int j = 0; j < 16; ++j) {
                    const int q = lx + j;
                    x[j] = (q >= 0 && q < LL_) ? xrow[q] : 0.0f;
                }
            }
            const float* wp = &s_w[(c * O_TILE + og * 4) * T_PAD];
            #pragma unroll
            for (int o = 0; o < 4; ++o) {
                #pragma unroll
                for (int t = 0; t < KS_; ++t) {
                    const float wv = wp[o * T_PAD + t];
                    #pragma unroll
                    for (int j = 0; j < 8; ++j)
                        acc[o][j] = fmaf(wv, x[j + t], acc[o][j]);
                }
            }
        }

        float* yb = Y + ((size_t)(b * C_OUTP + o_base + og * 4)) * LL_ + l0;
        #pragma unroll
        for (int o = 0; o < 4; ++o) {
            float4 r0, r1;
            r0.x = acc[o][0] + bt[o]; r0.y = acc[o][1] + bt[o];
            r0.z = acc[o][2] + bt[o]; r0.w = acc[o][3] + bt[o];
            r1.x = acc[o][4] + bt[o]; r1.y = acc[o][5] + bt[o];
            r1.z = acc[o][6] + bt[o]; r1.w = acc[o][7] + bt[o];
            float4* yp = reinterpret_cast<float4*>(yb + (size_t)o * LL_);
            yp[0] = r0; yp[1] = r1;
        }
    }
}

// ---------------------------------------------------------------------------
extern "C" void kernel_launch(void* const* d_in, const int* in_sizes, int n_in,
                              void* d_out, int out_size, void* d_ws, size_t ws_size,
                              hipStream_t stream)
{
    const float* X         = (const float*)d_in[0];
    const float* Z         = (const float*)d_in[1];
    const float* z_in_w    = (const float*)d_in[2];
    const float* z_in_b    = (const float*)d_in[3];
    const float* w1        = (const float*)d_in[4];
    const float* b1        = (const float*)d_in[5];
    const float* w2        = (const float*)d_in[6];
    const float* b2        = (const float*)d_in[7];
    const float* bank      = (const float*)d_in[8];
    const float* bias_bank = (const float*)d_in[9];
    float* out = (float*)d_out;

    // workspace layout
    char* ws = (char*)d_ws;
    float* omega  = (float*)ws;                               // 256 f = 1 KB
    float* btilde = (float*)(ws + 1024);                      // 8192 f = 32 KB
    ushort_t* wt  = (ushort_t*)(ws + 1024 + 32768);           // 18,874,368 B
    ushort_t* XT  = (ushort_t*)(ws + 1024 + 32768 + (size_t)B_ * KS_ * C_OUTP * C_INP * 2);
    const size_t WS_NEEDED = 1024 + 32768
        + (size_t)B_ * KS_ * C_OUTP * C_INP * 2
        + (size_t)B_ * LPAD * C_INP * 2;                      // ~52.5 MB

    routing_kernel<<<B_, 256, 0, stream>>>(Z, z_in_w, z_in_b, w1, b1, w2, b2,
                                           bias_bank, omega, btilde);

    if (ws_size >= WS_NEEDED) {
        mix_kernel<<<C_OUTP, 256, 0, stream>>>(bank, omega, wt);
        transpose_kernel<<<dim3(LL_ / 64, B_), 256, 0, stream>>>(X, XT);
        gemm_kernel<<<2048, 256, 0, stream>>>(XT, wt, btilde, out);
    } else {
        dim3 grid(C_OUTP / O_TILE, B_);
        conv_kernel<<<grid, 256, 0, stream>>>(X, bank, omega, btilde, out);
    }
}